// Round 5
// baseline (859.869 us; speedup 1.0000x reference)
//
#include <hip/hip_runtime.h>
#include <hip/hip_bf16.h>
#include <math.h>

// ---------------- problem constants ----------------
#define OC     256
#define IC     128
#define HW     56
#define NB     64
#define KK     1152          // IC*9
#define HP     58            // padded spatial
#define PIX    (HW*HW)       // 3136
#define XPAD_ELEMS ((long)NB*HP*HP*IC)   // 27,557,888
#define A_ELEMS    (OC*KK)               // 294,912

typedef __attribute__((ext_vector_type(8))) short          bf16x8;
typedef __attribute__((ext_vector_type(8))) unsigned short u16x8;
typedef __attribute__((ext_vector_type(4))) float          f32x4;

__device__ __forceinline__ void async_load16(const void* g, void* l) {
    __builtin_amdgcn_global_load_lds(
        (const __attribute__((address_space(1))) void*)g,
        (__attribute__((address_space(3))) void*)l, 16, 0, 0);
}

// bf16 RNE convert
__device__ __forceinline__ unsigned short f2bf(float f) {
    unsigned int u = __float_as_uint(f);
    return (unsigned short)((u + 0x7fffu + ((u >> 16) & 1u)) >> 16);
}
__device__ __forceinline__ float bf2f(unsigned short b) {
    return __uint_as_float(((unsigned int)b) << 16);
}

// XOR-swizzled LDS element offset (2-way bank aliasing only — free, m136)
__device__ __forceinline__ int lds_off(int row, int q) {
    return row * 32 + (((q ^ (row >> 1)) & 3) << 3);
}

// ---------------- kernel 1: weights + BN constants ----------------
__global__ __launch_bounds__(256) void prep_weights(
        const float* __restrict__ phase, const float* __restrict__ gamma,
        const float* __restrict__ beta,  const float* __restrict__ rmean,
        const float* __restrict__ rvar,
        __hip_bfloat16* __restrict__ ah, __hip_bfloat16* __restrict__ al,
        float* __restrict__ scale, float* __restrict__ bias) {
    int g = blockIdx.x * 256 + threadIdx.x;      // 0 .. 294911
    int oc = g / KK;
    int kk = g - oc * KK;
    int kpos = kk >> 7;          // kh*3+kw
    int ic   = kk & 127;
    int j    = ic * 9 + kpos;    // original flat k = ic*9 + kh*3 + kw
    int pidx = (((oc >> 3) * 144 + (j >> 3)) * 8 + (oc & 7)) * 8 + (j & 7);
    double phi = (double)phase[pidx];
    double c   = cos(phi);
    const double a = 0.987, r = 0.99;
    double num = a*a - 2.0*a*r*c + r*r;
    double den = 1.0 - 2.0*a*r*c + (a*r)*(a*r);
    float t = (float)(num / den);
    unsigned short hb = f2bf(t);
    float hf = bf2f(hb);
    ((unsigned short*)ah)[g] = hb;
    ((unsigned short*)al)[g] = f2bf(t - hf);
    if (g < OC) {
        float inv = gamma[g] / sqrtf(rvar[g] + 1e-5f);
        scale[g] = inv;
        bias[g]  = beta[g] - rmean[g] * inv;
    }
}

// ---------------- kernel 2: pad + transpose + bf16 hi/lo split ----------------
__global__ __launch_bounds__(256) void prep_x(
        const float* __restrict__ x,
        __hip_bfloat16* __restrict__ xh, __hip_bfloat16* __restrict__ xl) {
    int hp  = blockIdx.x;    // 0..57
    int img = blockIdx.y;    // 0..63
    __shared__ float tile[IC * 57];   // [ic][w], stride 57
    int t = threadIdx.x;
    bool border = (hp == 0) || (hp == HP - 1);
    if (!border) {
        int h = hp - 1;
        const float* src = x + (long)img * IC * PIX + h * HW;
#pragma unroll
        for (int i = 0; i < 7; ++i) {            // 128*14 float4 = 1792
            int idx = i * 256 + t;
            int ic  = idx / 14;
            int w4  = (idx - ic * 14) * 4;
            float4 v = *(const float4*)&src[(long)ic * PIX + w4];
            tile[ic * 57 + w4 + 0] = v.x;
            tile[ic * 57 + w4 + 1] = v.y;
            tile[ic * 57 + w4 + 2] = v.z;
            tile[ic * 57 + w4 + 3] = v.w;
        }
    }
    __syncthreads();
    long base = ((long)(img * HP + hp)) * HP * IC;
#pragma unroll
    for (int i = 0; i < 4; ++i) {                // 58*16 = 928 vec-tasks
        int v = i * 256 + t;
        if (v < 928) {
            int icg = v & 15;                    // 8 ic per task
            int wp  = v >> 4;                    // 0..57
            bool inw = !border && wp >= 1 && wp <= HW;
            u16x8 hv, lv;
#pragma unroll
            for (int j = 0; j < 8; ++j) {
                float f = inw ? tile[(icg * 8 + j) * 57 + (wp - 1)] : 0.f;
                unsigned short hb = f2bf(f);
                hv[j] = hb;
                lv[j] = f2bf(f - bf2f(hb));
            }
            long o = base + wp * IC + icg * 8;
            *(u16x8*)&((unsigned short*)xh)[o] = hv;
            *(u16x8*)&((unsigned short*)xl)[o] = lv;
        }
    }
}

// ---------------- kernel 3: implicit GEMM conv + BN + ReLU6 ----------------
// A fragments: DIRECT global->VGPR (L2/L1-resident, MFMA-layout addressing).
// B: LDS double-buffer + register fragment double-buffer.
//   per chunk: sync -> issue B staging(c+2) -> load A(c+1) global -> ds_read B(c+1) -> MFMA(c)
__global__ __launch_bounds__(256, 2) void conv_gemm(
        const __hip_bfloat16* __restrict__ ah, const __hip_bfloat16* __restrict__ al,
        const __hip_bfloat16* __restrict__ xh, const __hip_bfloat16* __restrict__ xl,
        const float* __restrict__ scale, const float* __restrict__ bias,
        float* __restrict__ out) {
    __shared__ __hip_bfloat16 sBh0[4096], sBl0[4096];
    __shared__ __hip_bfloat16 sBh1[4096], sBl1[4096];

    int bid = blockIdx.x;
    int img = bid / 50;
    int rem = bid - img * 50;
    int mt  = rem >> 1;      // 0..24  pixel tile
    int ot  = rem & 1;       // oc tile

    int t    = threadIdx.x;
    int lane = t & 63;
    int wave = t >> 6;
    int wm   = wave & 1;     // oc half (64)
    int wn   = wave >> 1;    // pixel half (64)

    int row0 = t >> 2;
    int col0 = (((t & 3) ^ ((t >> 3) & 3))) << 3;

    // A direct-load base: lane l covers A[m = l&15][k = (l>>4)*8 + j]
    const __hip_bfloat16* pAh = ah + (long)(ot * 128 + wm * 64 + (lane & 15)) * KK + ((lane >> 4) << 3);
    const __hip_bfloat16* pAl = al + (long)(ot * 128 + wm * 64 + (lane & 15)) * KK + ((lane >> 4) << 3);

    int m0 = mt * 128 + row0;      if (m0 > PIX - 1) m0 = PIX - 1;
    int m1 = mt * 128 + row0 + 64; if (m1 > PIX - 1) m1 = PIX - 1;
    int h0 = m0 / HW, w0 = m0 - h0 * HW;
    int h1 = m1 / HW, w1 = m1 - h1 * HW;
    const __hip_bfloat16* pxh0 = xh + (long)((img * HP + h0) * HP + w0) * IC + col0;
    const __hip_bfloat16* pxh1 = xh + (long)((img * HP + h1) * HP + w1) * IC + col0;
    const __hip_bfloat16* pxl0 = xl + (long)((img * HP + h0) * HP + w0) * IC + col0;
    const __hip_bfloat16* pxl1 = xl + (long)((img * HP + h1) * HP + w1) * IC + col0;

    int br[4];
#pragma unroll
    for (int f = 0; f < 4; ++f)
        br[f] = lds_off(wn * 64 + f * 16 + (lane & 15), lane >> 4);

    f32x4 acc[4][4];
#pragma unroll
    for (int i = 0; i < 4; ++i)
#pragma unroll
        for (int jj = 0; jj < 4; ++jj) acc[i][jj] = (f32x4){0.f, 0.f, 0.f, 0.f};

    bf16x8 aH0[4], aL0[4], bH0[4], bL0[4];
    bf16x8 aH1[4], aL1[4], bH1[4], bL1[4];

#define ISSUE(ci, SBH, SBL)                                                     \
    {                                                                           \
        int bs = 32 * (ci) + ((ci) >= 12 ? 7040 : 0) + ((ci) >= 24 ? 7040 : 0); \
        async_load16(pxh0 + bs, &SBH[t * 8]);                                   \
        async_load16(pxh1 + bs, &SBH[2048 + t * 8]);                            \
        async_load16(pxl0 + bs, &SBL[t * 8]);                                   \
        async_load16(pxl1 + bs, &SBL[2048 + t * 8]);                            \
    }

#define AREAD(ci, AH, AL)                                                       \
    {                                                                           \
        long ao = (long)(ci) * 32;                                              \
        _Pragma("unroll")                                                       \
        for (int f = 0; f < 4; ++f) {                                           \
            AH[f] = *(const bf16x8*)(pAh + ao + (long)f * 16 * KK);             \
            AL[f] = *(const bf16x8*)(pAl + ao + (long)f * 16 * KK);             \
        }                                                                       \
    }

#define BREAD(BH, BL, SBH, SBL)                                                 \
    {                                                                           \
        _Pragma("unroll")                                                       \
        for (int f = 0; f < 4; ++f) {                                           \
            BH[f] = *(const bf16x8*)&SBH[br[f]];                                \
            BL[f] = *(const bf16x8*)&SBL[br[f]];                                \
        }                                                                       \
    }

#define MFMAS(AH, AL, BH, BL)                                                   \
    {                                                                           \
        _Pragma("unroll")                                                       \
        for (int fm = 0; fm < 4; ++fm)                                          \
            _Pragma("unroll")                                                   \
            for (int fn = 0; fn < 4; ++fn) {                                    \
                acc[fm][fn] = __builtin_amdgcn_mfma_f32_16x16x32_bf16(AL[fm], BH[fn], acc[fm][fn], 0, 0, 0); \
                acc[fm][fn] = __builtin_amdgcn_mfma_f32_16x16x32_bf16(AH[fm], BL[fn], acc[fm][fn], 0, 0, 0); \
                acc[fm][fn] = __builtin_amdgcn_mfma_f32_16x16x32_bf16(AH[fm], BH[fn], acc[fm][fn], 0, 0, 0); \
            }                                                                   \
    }

    // prologue
    ISSUE(0, sBh0, sBl0);
    AREAD(0, aH0, aL0);
    __syncthreads();
    ISSUE(1, sBh1, sBl1);
    BREAD(bH0, bL0, sBh0, sBl0);

#pragma unroll 1
    for (int cc = 0; cc < 18; ++cc) {
        int c = cc * 2;
        __syncthreads();                             // drains staging(c+1) + B reads(c)
        if (c + 2 < 36) ISSUE(c + 2, sBh0, sBl0);
        AREAD(c + 1, aH1, aL1);
        BREAD(bH1, bL1, sBh1, sBl1);
        MFMAS(aH0, aL0, bH0, bL0);                   // chunk c
        __syncthreads();
        if (c + 3 < 36) ISSUE(c + 3, sBh1, sBl1);
        if (c + 2 < 36) { AREAD(c + 2, aH0, aL0); BREAD(bH0, bL0, sBh0, sBl0); }
        MFMAS(aH1, aL1, bH1, bL1);                   // chunk c+1
    }
#undef ISSUE
#undef AREAD
#undef BREAD
#undef MFMAS

    // epilogue: BN (eval) + ReLU6, store fp32
    int pixc = mt * 128 + wn * 64 + (lane & 15);
    int occ0 = ot * 128 + wm * 64 + ((lane >> 4) << 2);
#pragma unroll
    for (int fm = 0; fm < 4; ++fm) {
#pragma unroll
        for (int r = 0; r < 4; ++r) {
            int oc = occ0 + fm * 16 + r;
            float sc = scale[oc], bi = bias[oc];
            long obase = ((long)(img * OC + oc)) * PIX;
#pragma unroll
            for (int fn = 0; fn < 4; ++fn) {
                int pix = pixc + fn * 16;
                if (pix < PIX) {
                    float v = acc[fm][fn][r] * sc + bi;
                    v = fminf(fmaxf(v, 0.f), 6.f);
                    out[obase + pix] = v;
                }
            }
        }
    }
}

// ---------------- launch ----------------
extern "C" void kernel_launch(void* const* d_in, const int* in_sizes, int n_in,
                              void* d_out, int out_size, void* d_ws, size_t ws_size,
                              hipStream_t stream) {
    const float* x     = (const float*)d_in[0];
    const float* phase = (const float*)d_in[1];
    const float* gamma = (const float*)d_in[2];
    const float* beta  = (const float*)d_in[3];
    const float* rmean = (const float*)d_in[4];
    const float* rvar  = (const float*)d_in[5];
    float* out = (float*)d_out;

    __hip_bfloat16* xh = (__hip_bfloat16*)d_ws;
    __hip_bfloat16* xl = xh + XPAD_ELEMS;
    __hip_bfloat16* ah = xl + XPAD_ELEMS;
    __hip_bfloat16* al = ah + A_ELEMS;
    float* scale = (float*)(al + A_ELEMS);
    float* bias  = scale + OC;

    prep_weights<<<A_ELEMS / 256, 256, 0, stream>>>(phase, gamma, beta, rmean, rvar,
                                                    ah, al, scale, bias);
    prep_x<<<dim3(HP, NB), 256, 0, stream>>>(x, xh, xl);
    conv_gemm<<<NB * 50, 256, 0, stream>>>(ah, al, xh, xl, scale, bias, out);
}

// Round 6
// 596.363 us; speedup vs baseline: 1.4419x; 1.4419x over previous
//
#include <hip/hip_runtime.h>
#include <hip/hip_bf16.h>
#include <math.h>

// ---------------- problem constants ----------------
#define OC     256
#define IC     128
#define HW     56
#define NB     64
#define KK     1152          // IC*9
#define HP     58            // padded spatial
#define PIX    (HW*HW)       // 3136
#define XPAD_ELEMS ((long)NB*HP*HP*IC)   // 27,557,888
#define A_ELEMS    (OC*KK)               // 294,912

typedef __attribute__((ext_vector_type(8))) short          bf16x8;
typedef __attribute__((ext_vector_type(8))) unsigned short u16x8;
typedef __attribute__((ext_vector_type(4))) float          f32x4;

__device__ __forceinline__ void async_load16(const void* g, void* l) {
    __builtin_amdgcn_global_load_lds(
        (const __attribute__((address_space(1))) void*)g,
        (__attribute__((address_space(3))) void*)l, 16, 0, 0);
}

// bf16 RNE convert
__device__ __forceinline__ unsigned short f2bf(float f) {
    unsigned int u = __float_as_uint(f);
    return (unsigned short)((u + 0x7fffu + ((u >> 16) & 1u)) >> 16);
}
__device__ __forceinline__ float bf2f(unsigned short b) {
    return __uint_as_float(((unsigned int)b) << 16);
}

// XOR-swizzled LDS element offset (2-way bank aliasing only — free, m136)
__device__ __forceinline__ int lds_off(int row, int q) {
    return row * 32 + (((q ^ (row >> 1)) & 3) << 3);
}

// ---------------- kernel 1: weights + BN constants ----------------
__global__ __launch_bounds__(256) void prep_weights(
        const float* __restrict__ phase, const float* __restrict__ gamma,
        const float* __restrict__ beta,  const float* __restrict__ rmean,
        const float* __restrict__ rvar,
        __hip_bfloat16* __restrict__ ah, __hip_bfloat16* __restrict__ al,
        float* __restrict__ scale, float* __restrict__ bias) {
    int g = blockIdx.x * 256 + threadIdx.x;      // 0 .. 294911
    int oc = g / KK;
    int kk = g - oc * KK;
    int kpos = kk >> 7;          // kh*3+kw
    int ic   = kk & 127;
    int j    = ic * 9 + kpos;    // original flat k = ic*9 + kh*3 + kw
    int pidx = (((oc >> 3) * 144 + (j >> 3)) * 8 + (oc & 7)) * 8 + (j & 7);
    double phi = (double)phase[pidx];
    double c   = cos(phi);
    const double a = 0.987, r = 0.99;
    double num = a*a - 2.0*a*r*c + r*r;
    double den = 1.0 - 2.0*a*r*c + (a*r)*(a*r);
    float t = (float)(num / den);
    unsigned short hb = f2bf(t);
    float hf = bf2f(hb);
    ((unsigned short*)ah)[g] = hb;
    ((unsigned short*)al)[g] = f2bf(t - hf);
    if (g < OC) {
        float inv = gamma[g] / sqrtf(rvar[g] + 1e-5f);
        scale[g] = inv;
        bias[g]  = beta[g] - rmean[g] * inv;
    }
}

// ---------------- kernel 2: pad + transpose + bf16 hi/lo split ----------------
__global__ __launch_bounds__(256) void prep_x(
        const float* __restrict__ x,
        __hip_bfloat16* __restrict__ xh, __hip_bfloat16* __restrict__ xl) {
    int hp  = blockIdx.x;    // 0..57
    int img = blockIdx.y;    // 0..63
    __shared__ float tile[IC * 57];   // [ic][w], stride 57
    int t = threadIdx.x;
    bool border = (hp == 0) || (hp == HP - 1);
    if (!border) {
        int h = hp - 1;
        const float* src = x + (long)img * IC * PIX + h * HW;
#pragma unroll
        for (int i = 0; i < 7; ++i) {            // 128*14 float4 = 1792
            int idx = i * 256 + t;
            int ic  = idx / 14;
            int w4  = (idx - ic * 14) * 4;
            float4 v = *(const float4*)&src[(long)ic * PIX + w4];
            tile[ic * 57 + w4 + 0] = v.x;
            tile[ic * 57 + w4 + 1] = v.y;
            tile[ic * 57 + w4 + 2] = v.z;
            tile[ic * 57 + w4 + 3] = v.w;
        }
    }
    __syncthreads();
    long base = ((long)(img * HP + hp)) * HP * IC;
#pragma unroll
    for (int i = 0; i < 4; ++i) {                // 58*16 = 928 vec-tasks
        int v = i * 256 + t;
        if (v < 928) {
            int icg = v & 15;                    // 8 ic per task
            int wp  = v >> 4;                    // 0..57
            bool inw = !border && wp >= 1 && wp <= HW;
            u16x8 hv, lv;
#pragma unroll
            for (int j = 0; j < 8; ++j) {
                float f = inw ? tile[(icg * 8 + j) * 57 + (wp - 1)] : 0.f;
                unsigned short hb = f2bf(f);
                hv[j] = hb;
                lv[j] = f2bf(f - bf2f(hb));
            }
            long o = base + wp * IC + icg * 8;
            *(u16x8*)&((unsigned short*)xh)[o] = hv;
            *(u16x8*)&((unsigned short*)xl)[o] = lv;
        }
    }
}

// ---------------- kernel 3: implicit GEMM conv + BN + ReLU6 ----------------
// LDS double-buffer + register fragment double-buffer (R4 structure) +
// XCD-aware swizzle: XCD x works on imgs [x*8, x*8+8) so each img's xh/xl
// (1.72 MB) is L2-resident on ONE XCD; ot-pair + mt-halo reuse hit L2.
__global__ __launch_bounds__(256, 2) void conv_gemm(
        const __hip_bfloat16* __restrict__ ah, const __hip_bfloat16* __restrict__ al,
        const __hip_bfloat16* __restrict__ xh, const __hip_bfloat16* __restrict__ xl,
        const float* __restrict__ scale, const float* __restrict__ bias,
        float* __restrict__ out) {
    __shared__ __hip_bfloat16 sAh0[4096], sAl0[4096], sBh0[4096], sBl0[4096];
    __shared__ __hip_bfloat16 sAh1[4096], sAl1[4096], sBh1[4096], sBl1[4096];

    // XCD-aware swizzle: consecutive blockIdx -> XCD round-robin (b&7).
    int b   = blockIdx.x;
    int xcd = b & 7;
    int idx = b >> 3;            // 0..399 per XCD
    int img = xcd * 8 + idx / 50;
    int rem = idx % 50;
    int mt  = rem >> 1;          // 0..24  pixel tile
    int ot  = rem & 1;           // oc tile

    int t    = threadIdx.x;
    int lane = t & 63;
    int wave = t >> 6;
    int wm   = wave & 1;     // oc half (64)
    int wn   = wave >> 1;    // pixel half (64)

    int row0 = t >> 2;
    int col0 = (((t & 3) ^ ((t >> 3) & 3))) << 3;

    const __hip_bfloat16* pah0 = ah + (long)(ot * 128 + row0) * KK + col0;
    const __hip_bfloat16* pah1 = pah0 + (long)64 * KK;
    const __hip_bfloat16* pal0 = al + (long)(ot * 128 + row0) * KK + col0;
    const __hip_bfloat16* pal1 = pal0 + (long)64 * KK;

    int m0 = mt * 128 + row0;      if (m0 > PIX - 1) m0 = PIX - 1;
    int m1 = mt * 128 + row0 + 64; if (m1 > PIX - 1) m1 = PIX - 1;
    int h0 = m0 / HW, w0 = m0 - h0 * HW;
    int h1 = m1 / HW, w1 = m1 - h1 * HW;
    const __hip_bfloat16* pxh0 = xh + (long)((img * HP + h0) * HP + w0) * IC + col0;
    const __hip_bfloat16* pxh1 = xh + (long)((img * HP + h1) * HP + w1) * IC + col0;
    const __hip_bfloat16* pxl0 = xl + (long)((img * HP + h0) * HP + w0) * IC + col0;
    const __hip_bfloat16* pxl1 = xl + (long)((img * HP + h1) * HP + w1) * IC + col0;

    int ar[4], br[4];
#pragma unroll
    for (int f = 0; f < 4; ++f) {
        ar[f] = lds_off(wm * 64 + f * 16 + (lane & 15), lane >> 4);
        br[f] = lds_off(wn * 64 + f * 16 + (lane & 15), lane >> 4);
    }

    f32x4 acc[4][4];
#pragma unroll
    for (int i = 0; i < 4; ++i)
#pragma unroll
        for (int jj = 0; jj < 4; ++jj) acc[i][jj] = (f32x4){0.f, 0.f, 0.f, 0.f};

    bf16x8 aH0[4], aL0[4], bH0[4], bL0[4];
    bf16x8 aH1[4], aL1[4], bH1[4], bL1[4];

#define ISSUE(ci, SAH, SAL, SBH, SBL)                                          \
    {                                                                           \
        int bs = 32 * (ci) + ((ci) >= 12 ? 7040 : 0) + ((ci) >= 24 ? 7040 : 0); \
        long a0 = (long)(ci) * 32;                                              \
        async_load16(pah0 + a0, &SAH[t * 8]);                                   \
        async_load16(pah1 + a0, &SAH[2048 + t * 8]);                            \
        async_load16(pal0 + a0, &SAL[t * 8]);                                   \
        async_load16(pal1 + a0, &SAL[2048 + t * 8]);                            \
        async_load16(pxh0 + bs, &SBH[t * 8]);                                   \
        async_load16(pxh1 + bs, &SBH[2048 + t * 8]);                            \
        async_load16(pxl0 + bs, &SBL[t * 8]);                                   \
        async_load16(pxl1 + bs, &SBL[2048 + t * 8]);                            \
    }

#define READF(AH, AL, BH, BL, SAH, SAL, SBH, SBL)                               \
    {                                                                           \
        _Pragma("unroll")                                                       \
        for (int f = 0; f < 4; ++f) {                                           \
            AH[f] = *(const bf16x8*)&SAH[ar[f]];                                \
            AL[f] = *(const bf16x8*)&SAL[ar[f]];                                \
            BH[f] = *(const bf16x8*)&SBH[br[f]];                                \
            BL[f] = *(const bf16x8*)&SBL[br[f]];                                \
        }                                                                       \
    }

#define MFMAS(AH, AL, BH, BL)                                                   \
    {                                                                           \
        _Pragma("unroll")                                                       \
        for (int fm = 0; fm < 4; ++fm)                                          \
            _Pragma("unroll")                                                   \
            for (int fn = 0; fn < 4; ++fn) {                                    \
                acc[fm][fn] = __builtin_amdgcn_mfma_f32_16x16x32_bf16(AL[fm], BH[fn], acc[fm][fn], 0, 0, 0); \
                acc[fm][fn] = __builtin_amdgcn_mfma_f32_16x16x32_bf16(AH[fm], BL[fn], acc[fm][fn], 0, 0, 0); \
                acc[fm][fn] = __builtin_amdgcn_mfma_f32_16x16x32_bf16(AH[fm], BH[fn], acc[fm][fn], 0, 0, 0); \
            }                                                                   \
    }

    // prologue: stage 0, drain, stage 1, read frags(0)
    ISSUE(0, sAh0, sAl0, sBh0, sBl0);
    __syncthreads();
    ISSUE(1, sAh1, sAl1, sBh1, sBl1);
    READF(aH0, aL0, bH0, bL0, sAh0, sAl0, sBh0, sBl0);

#pragma unroll 1
    for (int cc = 0; cc < 18; ++cc) {
        int c = cc * 2;
        __syncthreads();                                   // drains staging(c+1) + frag reads(c)
        if (c + 2 < 36) ISSUE(c + 2, sAh0, sAl0, sBh0, sBl0);
        READF(aH1, aL1, bH1, bL1, sAh1, sAl1, sBh1, sBl1); // frags(c+1)
        MFMAS(aH0, aL0, bH0, bL0);                         // chunk c
        __syncthreads();
        if (c + 3 < 36) ISSUE(c + 3, sAh1, sAl1, sBh1, sBl1);
        if (c + 2 < 36) READF(aH0, aL0, bH0, bL0, sAh0, sAl0, sBh0, sBl0);
        MFMAS(aH1, aL1, bH1, bL1);                         // chunk c+1
    }
#undef ISSUE
#undef READF
#undef MFMAS

    // epilogue: BN (eval) + ReLU6, store fp32
    int pixc = mt * 128 + wn * 64 + (lane & 15);
    int occ0 = ot * 128 + wm * 64 + ((lane >> 4) << 2);
#pragma unroll
    for (int fm = 0; fm < 4; ++fm) {
#pragma unroll
        for (int r = 0; r < 4; ++r) {
            int oc = occ0 + fm * 16 + r;
            float sc = scale[oc], bi = bias[oc];
            long obase = ((long)(img * OC + oc)) * PIX;
#pragma unroll
            for (int fn = 0; fn < 4; ++fn) {
                int pix = pixc + fn * 16;
                if (pix < PIX) {
                    float v = acc[fm][fn][r] * sc + bi;
                    v = fminf(fmaxf(v, 0.f), 6.f);
                    out[obase + pix] = v;
                }
            }
        }
    }
}

// ---------------- launch ----------------
extern "C" void kernel_launch(void* const* d_in, const int* in_sizes, int n_in,
                              void* d_out, int out_size, void* d_ws, size_t ws_size,
                              hipStream_t stream) {
    const float* x     = (const float*)d_in[0];
    const float* phase = (const float*)d_in[1];
    const float* gamma = (const float*)d_in[2];
    const float* beta  = (const float*)d_in[3];
    const float* rmean = (const float*)d_in[4];
    const float* rvar  = (const float*)d_in[5];
    float* out = (float*)d_out;

    __hip_bfloat16* xh = (__hip_bfloat16*)d_ws;
    __hip_bfloat16* xl = xh + XPAD_ELEMS;
    __hip_bfloat16* ah = xl + XPAD_ELEMS;
    __hip_bfloat16* al = ah + A_ELEMS;
    float* scale = (float*)(al + A_ELEMS);
    float* bias  = scale + OC;

    prep_weights<<<A_ELEMS / 256, 256, 0, stream>>>(phase, gamma, beta, rmean, rvar,
                                                    ah, al, scale, bias);
    prep_x<<<dim3(HP, NB), 256, 0, stream>>>(x, xh, xl);
    conv_gemm<<<NB * 50, 256, 0, stream>>>(ah, al, xh, xl, scale, bias, out);
}